// Round 10
// baseline (541.852 us; speedup 1.0000x reference)
//
#include <hip/hip_runtime.h>
#include <hip/hip_fp16.h>
#include <math.h>

typedef _Float16 half8  __attribute__((ext_vector_type(8)));
typedef _Float16 half4v __attribute__((ext_vector_type(4)));
typedef _Float16 half2v __attribute__((ext_vector_type(2)));
typedef __fp16   fp16x2v __attribute__((ext_vector_type(2)));
typedef float    f32x4  __attribute__((ext_vector_type(4)));

#define MFMA_F16 __builtin_amdgcn_mfma_f32_16x16x32_f16

namespace {

constexpr int M_ROWS = 64;                   // rows per block (8 waves x 64x32 tile, 1x8 col split)
// XOR-swizzled packed layouts (granule = 8 halves = 16 B):
//   Haddr(m,n) = Hx_OFF + m*256 + (((n>>3) ^ (m&7))<<3) + (n&7)   each H: 32 KB
//   Paddr(m,k) = PE_OFF + m*64 + (((k>>3) ^ (m&7))<<3) + (k&7)    PE: 8 KB
// R28 == R27 resubmitted (round 9 died to a container-infra failure, no
// counters; hang-audit re-done: barrier counts template-uniform, visibility
// proven via entry-lgkm0-before-barrier, rotation math re-derived).
// R27 rationale: R26's 2x4 retile REVERTED (halved LDS conflicts as
// predicted but doubled A-path to ~103% of per-CU L2 share -> 388us).
// R25 ledger: MFMA 52%, L2-weights 51%, LDS 45%, VALU 33% -- phase-
// correlation bound (lockstep barriers burst one pipe at a time).
// Lever: CHUNK ROTATION. In the 1x8 tiling, H feature-chunk c of a layer's
// input is produced entirely by wave c -> wave w processes chunks
// (w, w+1, ..) mod 8, doing its OWN chunk pre-barrier (own epilogue writes,
// drained by entry lgkmcnt(0)). Layer = entry-lgkm0 -> A+bias+ownB+8 MFMA ->
// plain s_barrier -> 7 other chunks -> epilogue (no trailing barrier; next
// layer's internal barrier gates visibility). A-load for the first post-
// barrier chunk is issued pre-barrier and stays in flight across it.
// g2_0: stable pe_x chunks also pre-barrier (P=3). c_0: pe_d is fresh ->
// PE chunks post-barrier (P=1). g1_0: PE-only, no internal barrier.
// setprio around MFMA clusters + pk_max ReLU retained (R25, +10%).
constexpr int H0_OFF   = 0;                  // 16384 halves
constexpr int H1_OFF   = 16384;              // 16384 halves
constexpr int PE_OFF   = 32768;              // 4096 halves
constexpr int BIAS_OFF = 36864;              // 9*256 = 2304 halves
constexpr int LDS_HALVES = 39168;            // 78336 B -> 2 blocks/CU
constexpr size_t LDS_BYTES = (size_t)LDS_HALVES * sizeof(_Float16);

// Layer order: g1_0..g1_4, g2_0..g2_2, c_0, c_1, sig
constexpr int OFF_A[11] = {0,16384,81920,147456,212992,278528,360448,425984,491520,573440,577536};
constexpr int TOTAL_W   = 581632;   // fp16 elements in swizzled blob

struct Ptr11 { const float* p[11]; };

// Full barrier: drain LDS, then barrier (register-targeted global loads stay
// in flight; consumers get per-use vmcnt waits from the compiler).
__device__ __forceinline__ void lds_barrier() {
  asm volatile("s_waitcnt lgkmcnt(0)\n\ts_barrier" ::: "memory");
}
// Drain own LDS ops only (no barrier).
__device__ __forceinline__ void lgkm0() {
  asm volatile("s_waitcnt lgkmcnt(0)" ::: "memory");
}
// Plain barrier, no drain (each wave drained its writes at layer entry).
__device__ __forceinline__ void sbar() {
  asm volatile("s_barrier" ::: "memory");
}

// ---------------------------------------------------------------------------
// Weight pre-swizzle (R15/R18 layout, unchanged): lane-fastest order.
//   256-out layers: blob[((kc*16 + nt)*64 + lane)*8 + j]
//   heads (L=9,10): blob[(kc*64 + lane)*8 + j]
//   element = W[remap(kc*32 + (lane>>4)*8 + j)][nt*16 + (lane&15)], 0 if pad.
// ---------------------------------------------------------------------------
__global__ void prep_kernel(Ptr11 wp, _Float16* __restrict__ ws) {
  int tid = blockIdx.x * blockDim.x + threadIdx.x;
  if (tid >= TOTAL_W) return;
  int L = 0;
#pragma unroll
  for (int i = 1; i < 11; ++i) if (tid >= OFF_A[i]) L = i;
  int e    = tid - OFF_A[L];
  int l15  = e & 15;           // fastest: n&15 -> coalesced W reads
  int j    = (e >> 4) & 7;
  int khi  = (e >> 7) & 3;
  int rest = e >> 9;
  int kc, nt;
  if (L <= 8) { nt = rest & 15; kc = rest >> 4; }
  else        { nt = 0;         kc = rest;      }
  int lane = khi * 16 + l15;
  int n    = nt * 16 + l15;
  int kpad = kc * 32 + khi * 8 + j;
  int k;
  if      (L == 0) k = (kpad < 63) ? kpad : -1;                               // g1_0: din 63 pad->64
  else if (L == 5) k = (kpad < 64) ? ((kpad < 63) ? kpad : -1) : kpad - 1;    // g2_0: [pe_x 63|f1 256]
  else if (L == 8) k = (kpad < 64) ? ((kpad < 39) ? kpad : -1) : kpad - 25;   // c_0:  [pe_d 39|f2 256]
  else             k = kpad;                                                  // din 256 exact
  int dout = (L == 9) ? 3 : ((L == 10) ? 1 : 256);
  float v = 0.f;
  if (k >= 0 && n < dout) v = wp.p[L][k * dout + n];
  int idx = (L <= 8) ? OFF_A[L] + ((kc * 16 + nt) * 64 + lane) * 8 + j
                     : OFF_A[L] + (kc * 64 + lane) * 8 + j;
  ws[idx] = (_Float16)v;
}

// ---------------------------------------------------------------------------
// One 256-out linear layer, chunk-rotated. Wave cg (0..7): rows [0,64) x
// feats [cg*32,+32). Position sequence for wave cg:
//   PE_PRE:  [PE0..PE_{PE_CH-1}, H(cg), | barrier | H(cg+1)..H(cg+7)]
//   !PE_PRE: [H(cg), | barrier | PE0..PE_{PE_CH-1}, H(cg+1)..H(cg+7)]
//   H_CH==0: all PE, no barrier.
// H chunk t reads feature-chunk U=(cg+t)&7 of hin -- for t=0 that is the
// wave's OWN previous epilogue (drained by entry lgkm0). Epilogue writes
// hout != hin; cross-wave visibility gated by the NEXT layer's barrier.
// A: dist-1 ping-pong (first post-barrier A issued pre-barrier, in flight
// across it). B: bE/bO ping-pong; E/O base pre-swapped by cg parity so the
// +-co granule-XOR correction tracks the runtime chunk VALUE parity.
// setprio(1) fences MFMA clusters; ReLU via v_pk_max_f16 (exact numerics).
// ---------------------------------------------------------------------------
template <int PE_CH, int H_CH, bool PE_PRE, bool RELU>
__device__ __forceinline__ void do_layer_rot(_Float16* lds,
                                             const _Float16* __restrict__ hin,
                                             _Float16* __restrict__ hout,
                                             const _Float16* __restrict__ blob,
                                             int bias_idx, int cg, int lane) {
  constexpr int KCH = PE_CH + H_CH;   // 2, 8, or 10
  constexpr int P   = (H_CH > 0) ? ((PE_PRE ? PE_CH : 0) + 1) : KCH;
  const int l15  = lane & 15;
  const int quad = lane >> 4;
  const int s7   = l15 & 7;          // swizzle key (row&7 == l15&7)
  const int c1   = s7 >> 2;          // chunk-granule xor bit
  const int q3   = (quad ^ (s7 & 3));

  half8 aE[2], aO[2], bE[4], bO[4];

  // position -> chunk classification (I is an unrolled-literal; folds)
#define POS_IS_PE(I)  ((H_CH == 0) || (PE_PRE ? (I) < PE_CH                   \
                                             : ((I) >= 1 && (I) <= PE_CH)))
#define POS_PE_IDX(I) (PE_PRE || H_CH == 0 ? (I) : (I) - 1)
#define POS_H_T(I)    (PE_PRE ? (I) - PE_CH : ((I) == 0 ? 0 : (I) - PE_CH))

  // Blob col-tiles nt' = cg*2 + nt -> base offset (cg*128 + lane)*8.
  const _Float16* ap = blob + ((size_t)(cg * 128 + lane)) * 8;

#define LOADA_POS(dst, I)                                                     \
  {                                                                           \
    const int KC_ = POS_IS_PE(I) ? POS_PE_IDX(I)                              \
                                 : (PE_CH + ((cg + POS_H_T(I)) & 7));         \
    const _Float16* apk = ap + (size_t)KC_ * 8192;                            \
    _Pragma("unroll") for (int nt = 0; nt < 2; ++nt)                          \
        dst[nt] = *(const half8*)(apk + nt * 512);                            \
  }

  lgkm0();                 // own prior LDS writes (epilogue / pe_pass) retired
  LOADA_POS(aE, 0)         // issue earliest: covers bias-init below

  // Bias -> acc init (feature = cg*32 + nt*16 + quad*4 + i).
  f32x4 acc[4][2];
  {
    const _Float16* bb_ = lds + BIAS_OFF + bias_idx * 256 + cg * 32 + quad * 4;
#pragma unroll
    for (int nt = 0; nt < 2; ++nt) {
      half4v bh = *(const half4v*)(bb_ + nt * 16);
      f32x4 bf = { (float)bh[0], (float)bh[1], (float)bh[2], (float)bh[3] };
#pragma unroll
      for (int mt = 0; mt < 4; ++mt) acc[mt][nt] = bf;
    }
  }

  const _Float16* pebase = lds + PE_OFF + l15 * 64 + q3 * 8;
  const _Float16* hbase  = hin + l15 * 256 + q3 * 8;
  const int co = c1 << 5;            // 32-half parity correction
  const _Float16* peE = pebase + co;
  const _Float16* peO = pebase - co;
  const _Float16* hbE = hbase + co;
  const _Float16* hbO = hbase - co;
  // H chunk VALUE parity = (cg&1)^(t&1): pre-swap bases by cg parity so the
  // per-position select is the compile-time t parity.
  const _Float16* hbP0 = (cg & 1) ? hbO : hbE;   // t even
  const _Float16* hbP1 = (cg & 1) ? hbE : hbO;   // t odd

#define LOADB_POS(bb, I)                                                      \
  {                                                                           \
    if (POS_IS_PE(I)) {                                                       \
      const int PK_ = POS_PE_IDX(I);                                          \
      const _Float16* bpp = ((PK_ & 1) ? peO : peE) + PK_ * 32;               \
      _Pragma("unroll") for (int mt = 0; mt < 4; ++mt)                        \
          bb[mt] = *(const half8*)(bpp + mt * 1024);                          \
    } else {                                                                  \
      const int T_ = POS_H_T(I);                                              \
      const int U_ = (cg + T_) & 7;                                           \
      const _Float16* bpp = ((T_ & 1) ? hbP1 : hbP0) + U_ * 32;               \
      _Pragma("unroll") for (int mt = 0; mt < 4; ++mt)                        \
          bb[mt] = *(const half8*)(bpp + mt * 4096);                          \
    }                                                                         \
  }

#define DO_MFMA(ab, bb)                                                       \
  {                                                                           \
    _Pragma("unroll") for (int mt = 0; mt < 4; ++mt)                          \
        _Pragma("unroll") for (int nt = 0; nt < 2; ++nt)                      \
            acc[mt][nt] = MFMA_F16(ab[nt], bb[mt], acc[mt][nt], 0, 0, 0);     \
  }

  LOADB_POS(bE, 0)          // position 0 is always pre-barrier-safe
#pragma unroll
  for (int i = 0; i < KCH; ++i) {
    if (P < KCH && i == P) {           // first post-barrier position
      sbar();                          // plain: all waves drained at entry
      if (i & 1) { LOADB_POS(bO, i) } else { LOADB_POS(bE, i) }
    }
    if (i + 1 < KCH) {
      if (i & 1) { LOADA_POS(aE, i + 1) } else { LOADA_POS(aO, i + 1) }
      if (i + 1 != P) {                // can't pre-load the post-barrier B
        if (i & 1) { LOADB_POS(bE, i + 1) } else { LOADB_POS(bO, i + 1) }
      }
    }
    __builtin_amdgcn_s_setprio(1);
    if (i & 1) { DO_MFMA(aO, bO) } else { DO_MFMA(aE, bE) }
    __builtin_amdgcn_s_setprio(0);
  }
#undef LOADA_POS
#undef LOADB_POS
#undef DO_MFMA
#undef POS_IS_PE
#undef POS_PE_IDX
#undef POS_H_T

  // Epilogue (no barrier: hout != hin; next layer's internal barrier gates).
  // Feature n = cg*32 + nt*16 + quad*4 + j. Full granule
  // n>>3 = (cg>>1)*8 + ((cg&1)*4 | nt*2 | qb); XOR low 3 bits with s7.
  // Row m = mt*16 + l15 -> m*256 = mt*4096 + l15*256, m&7 == s7.
  const int qb = quad >> 1, q1 = quad & 1;
  const int cg4 = (cg & 1) * 4;
  _Float16* wbase = hout + l15 * 256 + (cg >> 1) * 64 + q1 * 4;
  _Float16* wps[2] = { wbase + (((cg4 | 0 | qb) ^ s7) << 3),
                       wbase + (((cg4 | 2 | qb) ^ s7) << 3) };
#pragma unroll
  for (int mt = 0; mt < 4; ++mt) {
#pragma unroll
    for (int nt = 0; nt < 2; ++nt) {
      f32x4 v = acc[mt][nt];
      fp16x2v lo = __builtin_amdgcn_cvt_pkrtz(v.x, v.y);
      fp16x2v hi = __builtin_amdgcn_cvt_pkrtz(v.z, v.w);
      uint2 pk = { __builtin_bit_cast(unsigned int, lo),
                   __builtin_bit_cast(unsigned int, hi) };
      if (RELU) {
        asm("v_pk_max_f16 %0, %1, 0" : "=v"(pk.x) : "v"(pk.x));
        asm("v_pk_max_f16 %0, %1, 0" : "=v"(pk.y) : "v"(pk.y));
      }
      *(uint2*)(wps[nt] + mt * 4096) = pk;
    }
  }
}

// Head (sig / c_1): NT=1 blob, K=256 over hin; wave w rows [w*16,+16), w<4.
__device__ __forceinline__ f32x4 head_mt(const _Float16* __restrict__ hin,
                                         const _Float16* __restrict__ blob,
                                         int w, int lane) {
  const int l15  = lane & 15;
  const int quad = lane >> 4;
  const int s7   = l15 & 7;
  const int c1   = s7 >> 2;
  const int q3   = (quad ^ (s7 & 3));
  const _Float16* hb = hin + (w * 16 + l15) * 256 + q3 * 8;
  f32x4 res = (f32x4)0.f;
#pragma unroll
  for (int kc = 0; kc < 8; ++kc) {
    half8 a = *(const half8*)(blob + (kc * 64 + lane) * 8);
    half8 b = *(const half8*)(hb + ((kc ^ c1) << 5));
    res = MFMA_F16(a, b, res, 0, 0, 0);
  }
  return res;
}

__device__ __forceinline__ void pe_classify(int f, int nfeat, int& mode, int& c,
                                            int& use_cos, float& freq) {
  mode = 2; c = 0; use_cos = 0; freq = 0.f;
  if (f < 3) { mode = 0; c = f; }
  else if (f < nfeat) {
    int g = f - 3, li = g / 6, rem = g - li * 6;
    use_cos = (rem >= 3); c = use_cos ? rem - 3 : rem;
    freq = (float)(1 << li); mode = 1;
  }
}

// Positional encoding (512 threads): thread owns feature pair (2fp, 2fp+1)
// for 4 rows (r = t*16 + rb, rb = tid>>5 in [0,16)) -> one aligned b32 store
// per row; swizzle key loop-invariant (r&7 == rb&7).
__device__ __forceinline__ void pe_pass(_Float16* lds, const float* __restrict__ src,
                                        int row0, int tid, int nfeat) {
  const int fp = tid & 31;           // feature pair 0..31
  const int rb = tid >> 5;           // row base 0..15
  int m0, c0, u0; float q0;
  int m1, c1_, u1; float q1;
  pe_classify(fp * 2,     nfeat, m0, c0,  u0, q0);
  pe_classify(fp * 2 + 1, nfeat, m1, c1_, u1, q1);
  const int swz = (((fp >> 2) ^ (rb & 7)) << 3) | ((fp & 3) * 2);
#pragma unroll
  for (int t = 0; t < 4; ++t) {
    int r = t * 16 + rb;
    float v0 = 0.f, v1 = 0.f;
    if (m0 == 0) v0 = src[(row0 + r) * 3 + c0];
    else if (m0 == 1) {
      float a = src[(row0 + r) * 3 + c0] * q0;
      v0 = u0 ? __cosf(a) : __sinf(a);
    }
    if (m1 == 0) v1 = src[(row0 + r) * 3 + c1_];
    else if (m1 == 1) {
      float a = src[(row0 + r) * 3 + c1_] * q1;
      v1 = u1 ? __cosf(a) : __sinf(a);
    }
    half2v hv = { (_Float16)v0, (_Float16)v1 };
    *(half2v*)(lds + PE_OFF + r * 64 + swz) = hv;
  }
}

__global__ __launch_bounds__(512, 4) void nerf_kernel(
    const _Float16* __restrict__ ws, const float* __restrict__ x,
    const float* __restrict__ dirp, Ptr11 bp, float* __restrict__ out) {
  extern __shared__ _Float16 lds[];
  const int tid  = threadIdx.x;
  const int lane = tid & 63;
  const int w    = tid >> 6;       // wave 0..7 (= col-group cg)
  const int l15  = lane & 15;
  const int quad = lane >> 4;
  const int row0 = blockIdx.x * M_ROWS;

  _Float16* H0 = lds + H0_OFF;
  _Float16* H1 = lds + H1_OFF;

  // ---- pe_x -> PE buffer; biases -> LDS (f16, b32 stores, once) ----
  pe_pass(lds, x, row0, tid, 63);
  for (int i = tid; i < 1152; i += 512) {       // 9*256 halves as 1152 dwords
    int L = i >> 7, e2 = (i & 127) * 2;
    half2v hv = { (_Float16)bp.p[L][e2], (_Float16)bp.p[L][e2 + 1] };
    *(half2v*)(lds + BIAS_OFF + L * 256 + e2) = hv;
  }
  lds_barrier();

  // ---- G1 (rotated; each layer's internal barrier gates prev epilogue) ----
  do_layer_rot<2, 0, true,  true >(lds, H0, H0, ws + OFF_A[0], 0, w, lane);
  do_layer_rot<0, 8, false, true >(lds, H0, H1, ws + OFF_A[1], 1, w, lane);
  do_layer_rot<0, 8, false, true >(lds, H1, H0, ws + OFF_A[2], 2, w, lane);
  do_layer_rot<0, 8, false, true >(lds, H0, H1, ws + OFF_A[3], 3, w, lane);
  do_layer_rot<0, 8, false, false>(lds, H1, H0, ws + OFF_A[4], 4, w, lane);  // f1 -> H0
  // ---- G2: pe_x stable -> PE chunks pre-barrier on g2_0 ----
  do_layer_rot<2, 8, true,  true >(lds, H0, H1, ws + OFF_A[5], 5, w, lane);  // pe_x last use
  do_layer_rot<0, 8, false, true >(lds, H1, H0, ws + OFF_A[6], 6, w, lane);
  do_layer_rot<0, 8, false, false>(lds, H0, H1, ws + OFF_A[7], 7, w, lane);  // f2 -> H1

  lds_barrier();     // all f2 epilogues visible for the sigma head

  // ---- sigma head reads f2 (waves 0..3); pe_d overwrites PE (pe_x dead) ----
  float sigv = 0.f;
  if (w < 4) {
    f32x4 sa = head_mt(H1, ws + OFF_A[10], w, lane);
    sigv = sa[0] + bp.p[10][0];   // valid in quad==0 lanes
  }
  pe_pass(lds, dirp, row0, tid, 39);

  // ---- color: c_0 [pe_d|f2] -> H0 (ReLU). PE_PRE=false: pe_d is gated by
  // c_0's internal barrier (entry lgkm0 drains each wave's pe writes). The
  // pre-barrier own-H chunk reads f2 (stable). ----
  do_layer_rot<2, 8, false, true>(lds, H1, H0, ws + OFF_A[8], 8, w, lane);
  lds_barrier();     // c_0 epilogues visible for the c_1 head
  if (w < 4) {
    f32x4 ca = head_mt(H0, ws + OFF_A[9], w, lane);
    if (quad == 0) {
      f32x4 o = { ca[0] + bp.p[9][0], ca[1] + bp.p[9][1], ca[2] + bp.p[9][2], sigv };
      *(f32x4*)(out + (size_t)(row0 + w * 16 + l15) * 4) = o;
    }
  }
}

}  // namespace

extern "C" void kernel_launch(void* const* d_in, const int* in_sizes, int n_in,
                              void* d_out, int out_size, void* d_ws, size_t ws_size,
                              hipStream_t stream) {
  const float* x   = (const float*)d_in[0];
  const float* dir = (const float*)d_in[1];
  Ptr11 wp, bp;
  for (int i = 0; i < 11; ++i) {
    wp.p[i] = (const float*)d_in[2 + 2 * i];
    bp.p[i] = (const float*)d_in[3 + 2 * i];
  }
  _Float16* ws = (_Float16*)d_ws;
  float* out = (float*)d_out;

  (void)hipFuncSetAttribute((const void*)nerf_kernel,
                            hipFuncAttributeMaxDynamicSharedMemorySize,
                            (int)LDS_BYTES);

  prep_kernel<<<(TOTAL_W + 255) / 256, 256, 0, stream>>>(wp, ws);
  nerf_kernel<<<262144 / M_ROWS, 512, LDS_BYTES, stream>>>(ws, x, dir, bp, out);
}

// Round 11
// 375.691 us; speedup vs baseline: 1.4423x; 1.4423x over previous
//
#include <hip/hip_runtime.h>
#include <hip/hip_fp16.h>
#include <math.h>

typedef _Float16 half8  __attribute__((ext_vector_type(8)));
typedef _Float16 half4v __attribute__((ext_vector_type(4)));
typedef _Float16 half2v __attribute__((ext_vector_type(2)));
typedef __fp16   fp16x2v __attribute__((ext_vector_type(2)));
typedef float    f32x4  __attribute__((ext_vector_type(4)));

#define MFMA_F16 __builtin_amdgcn_mfma_f32_16x16x32_f16

namespace {

constexpr int M_ROWS = 64;                   // rows per block (8 waves x 64x32 tile)
// XOR-swizzled packed layouts (granule = 8 halves = 16 B):
//   Haddr(m,n) = Hx_OFF + m*256 + (((n>>3) ^ (m&7))<<3) + (n&7)   each H: 32 KB
//   Paddr(m,k) = PE_OFF + m*64 + (((k>>3) ^ (m&7))<<3) + (k&7)    PE: 8 KB
// R29 == R25 restored (proven 285us kernel). The structural map is closed:
//  - 3-block residency: true reg demand 92/wave; every cap below spills
//    into the hot loop (R20: 684MB, R22: 158MB, R28: 640MB WRITE_SIZE).
//  - Row-split retile (R26): halves LDS conflicts as predicted but doubles
//    the A-path to ~103% of the per-CU L2 share -> -36%.
//  - Barrier reduction (R23): neutral; skew immaterial.
//  - Chunk rotation (R28): runtime chunk indices cost ~16 addressing regs
//    at a 0-headroom 128-reg cap -> spill.
//  - setprio around MFMA + pk_max ReLU (R25): -10%, kept here.
// Ledger at this kernel: MFMA 52%, L2-weights ~51%, LDS ~45-50%, VALU 33%,
// 2 lockstep phase domains -- a three-way pipe bind with residency pinned
// by registers. ~285us is this structure's ceiling.
constexpr int H0_OFF   = 0;                  // 16384 halves
constexpr int H1_OFF   = 16384;              // 16384 halves
constexpr int PE_OFF   = 32768;              // 4096 halves
constexpr int BIAS_OFF = 36864;              // 9*256 = 2304 halves
constexpr int LDS_HALVES = 39168;            // 78336 B -> 2 blocks/CU
constexpr size_t LDS_BYTES = (size_t)LDS_HALVES * sizeof(_Float16);

// Layer order: g1_0..g1_4, g2_0..g2_2, c_0, c_1, sig
constexpr int OFF_A[11] = {0,16384,81920,147456,212992,278528,360448,425984,491520,573440,577536};
constexpr int TOTAL_W   = 581632;   // fp16 elements in swizzled blob

struct Ptr11 { const float* p[11]; };

// Partial barrier: drain LDS only; register-targeted global loads stay in
// flight (consumers get per-use vmcnt waits from the compiler).
__device__ __forceinline__ void lds_barrier() {
  asm volatile("s_waitcnt lgkmcnt(0)\n\ts_barrier" ::: "memory");
}

// ---------------------------------------------------------------------------
// Weight pre-swizzle (R15/R18 layout, unchanged): lane-fastest order.
//   256-out layers: blob[((kc*16 + nt)*64 + lane)*8 + j]
//   heads (L=9,10): blob[(kc*64 + lane)*8 + j]
//   element = W[remap(kc*32 + (lane>>4)*8 + j)][nt*16 + (lane&15)], 0 if pad.
// ---------------------------------------------------------------------------
__global__ void prep_kernel(Ptr11 wp, _Float16* __restrict__ ws) {
  int tid = blockIdx.x * blockDim.x + threadIdx.x;
  if (tid >= TOTAL_W) return;
  int L = 0;
#pragma unroll
  for (int i = 1; i < 11; ++i) if (tid >= OFF_A[i]) L = i;
  int e    = tid - OFF_A[L];
  int l15  = e & 15;           // fastest: n&15 -> coalesced W reads
  int j    = (e >> 4) & 7;
  int khi  = (e >> 7) & 3;
  int rest = e >> 9;
  int kc, nt;
  if (L <= 8) { nt = rest & 15; kc = rest >> 4; }
  else        { nt = 0;         kc = rest;      }
  int lane = khi * 16 + l15;
  int n    = nt * 16 + l15;
  int kpad = kc * 32 + khi * 8 + j;
  int k;
  if      (L == 0) k = (kpad < 63) ? kpad : -1;                               // g1_0: din 63 pad->64
  else if (L == 5) k = (kpad < 64) ? ((kpad < 63) ? kpad : -1) : kpad - 1;    // g2_0: [pe_x 63|f1 256]
  else if (L == 8) k = (kpad < 64) ? ((kpad < 39) ? kpad : -1) : kpad - 25;   // c_0:  [pe_d 39|f2 256]
  else             k = kpad;                                                  // din 256 exact
  int dout = (L == 9) ? 3 : ((L == 10) ? 1 : 256);
  float v = 0.f;
  if (k >= 0 && n < dout) v = wp.p[L][k * dout + n];
  int idx = (L <= 8) ? OFF_A[L] + ((kc * 16 + nt) * 64 + lane) * 8 + j
                     : OFF_A[L] + (kc * 64 + lane) * 8 + j;
  ws[idx] = (_Float16)v;
}

// ---------------------------------------------------------------------------
// One 256-out linear layer; wave cg (0..7) computes rows [0,64) x cols
// [cg*32,+32). Reads hin (+ PE for PE_CH chunks), writes hout. NO internal
// barrier -- caller places one lds_barrier() after the call (H dbuf makes
// that sufficient). A: dist-1 ping-pong, chunk 0 at layer entry. B: bE/bO
// LDS ping-pong (R17/R21 proven). Dual-base swizzle SR (R9); compile-time
// reg indices (R1). Bias from LDS into acc (R18). Epilogue folds (cg&1)*4
// into the granule XOR. setprio(1) fences each MFMA cluster (T5: arbitrates
// between the 2 phase-domain blocks on a CU); ReLU via v_pk_max_f16 on the
// packed pair (identical numerics to f32 fmax+cvt).
// ---------------------------------------------------------------------------
template <int PE_CH, int H_CH, bool RELU>
__device__ __forceinline__ void do_layer(_Float16* lds,
                                         const _Float16* __restrict__ hin,
                                         _Float16* __restrict__ hout,
                                         const _Float16* __restrict__ blob,
                                         int bias_idx, int cg, int lane) {
  constexpr int KCH = PE_CH + H_CH;   // even (2, 8, or 10)
  const int l15  = lane & 15;
  const int quad = lane >> 4;
  const int s7   = l15 & 7;          // swizzle key (row&7 == l15&7)
  const int c1   = s7 >> 2;          // chunk-granule xor bit
  const int q3   = (quad ^ (s7 & 3));

  half8 aE[2], aO[2], bE[4], bO[4];

  // Blob col-tiles nt' = cg*2 + nt -> base offset cg*1024 + lane*8.
  const _Float16* ap = blob + ((size_t)(cg * 128 + lane)) * 8;

#define LOADA(dst, KCG)                                                       \
  {                                                                           \
    const _Float16* apk = ap + (size_t)(KCG) * 8192;                          \
    _Pragma("unroll") for (int nt = 0; nt < 2; ++nt)                          \
        dst[nt] = *(const half8*)(apk + nt * 512);                            \
  }

  LOADA(aE, 0)                       // issue earliest: covers bias-init below

  // Bias -> acc init (feature = cg*32 + nt*16 + quad*4 + i).
  f32x4 acc[4][2];
  {
    const _Float16* bb_ = lds + BIAS_OFF + bias_idx * 256 + cg * 32 + quad * 4;
#pragma unroll
    for (int nt = 0; nt < 2; ++nt) {
      half4v bh = *(const half4v*)(bb_ + nt * 16);
      f32x4 bf = { (float)bh[0], (float)bh[1], (float)bh[2], (float)bh[3] };
#pragma unroll
      for (int mt = 0; mt < 4; ++mt) acc[mt][nt] = bf;
    }
  }

  const _Float16* pebase = lds + PE_OFF + l15 * 64 + q3 * 8;
  const _Float16* hbase  = hin + l15 * 256 + q3 * 8;
  const int co = c1 << 5;            // 32-half parity correction
  const _Float16* peE = pebase + co;
  const _Float16* peO = pebase - co;
  const _Float16* hbE = hbase + co;
  const _Float16* hbO = hbase - co;

#define LOADB(bb, KCG)                                                        \
  {                                                                           \
    if ((KCG) < PE_CH) {                                                      \
      const _Float16* bpp = (((KCG) & 1) ? peO : peE) + (KCG) * 32;           \
      _Pragma("unroll") for (int mt = 0; mt < 4; ++mt)                        \
          bb[mt] = *(const half8*)(bpp + mt * 1024);                          \
    } else {                                                                  \
      const int U = (KCG) - PE_CH;                                            \
      const _Float16* bpp = ((U & 1) ? hbO : hbE) + U * 32;                   \
      _Pragma("unroll") for (int mt = 0; mt < 4; ++mt)                        \
          bb[mt] = *(const half8*)(bpp + mt * 4096);                          \
    }                                                                         \
  }

#define DO_MFMA(ab, bb)                                                       \
  {                                                                           \
    _Pragma("unroll") for (int mt = 0; mt < 4; ++mt)                          \
        _Pragma("unroll") for (int nt = 0; nt < 2; ++nt)                      \
            acc[mt][nt] = MFMA_F16(ab[nt], bb[mt], acc[mt][nt], 0, 0, 0);     \
  }

  LOADB(bE, 0)
#pragma unroll
  for (int kk = 0; kk < KCH; kk += 2) {
    LOADA(aO, kk + 1)
    LOADB(bO, kk + 1)
    __builtin_amdgcn_s_setprio(1);
    DO_MFMA(aE, bE)                  // chunk kk
    __builtin_amdgcn_s_setprio(0);
    if (kk + 2 < KCH) {
      LOADA(aE, kk + 2)
      LOADB(bE, kk + 2)
    }
    __builtin_amdgcn_s_setprio(1);
    DO_MFMA(aO, bO)                  // chunk kk+1
    __builtin_amdgcn_s_setprio(0);
  }
#undef LOADA
#undef LOADB
#undef DO_MFMA

  // Epilogue (no barrier needed first: hout != hin, and every wave's own
  // reads precede its writes in program order; cross-wave safety comes from
  // the caller's post-layer barrier).
  // Feature n = cg*32 + nt*16 + quad*4 + j. Full granule
  // n>>3 = (cg>>1)*8 + ((cg&1)*4 | nt*2 | qb); XOR low 3 bits with s7.
  // Row m = mt*16 + l15 -> m*256 = mt*4096 + l15*256, m&7 == s7.
  const int qb = quad >> 1, q1 = quad & 1;
  const int cg4 = (cg & 1) * 4;
  _Float16* wbase = hout + l15 * 256 + (cg >> 1) * 64 + q1 * 4;
  _Float16* wps[2] = { wbase + (((cg4 | 0 | qb) ^ s7) << 3),
                       wbase + (((cg4 | 2 | qb) ^ s7) << 3) };
#pragma unroll
  for (int mt = 0; mt < 4; ++mt) {
#pragma unroll
    for (int nt = 0; nt < 2; ++nt) {
      f32x4 v = acc[mt][nt];
      fp16x2v lo = __builtin_amdgcn_cvt_pkrtz(v.x, v.y);
      fp16x2v hi = __builtin_amdgcn_cvt_pkrtz(v.z, v.w);
      uint2 pk = { __builtin_bit_cast(unsigned int, lo),
                   __builtin_bit_cast(unsigned int, hi) };
      if (RELU) {
        asm("v_pk_max_f16 %0, %1, 0" : "=v"(pk.x) : "v"(pk.x));
        asm("v_pk_max_f16 %0, %1, 0" : "=v"(pk.y) : "v"(pk.y));
      }
      *(uint2*)(wps[nt] + mt * 4096) = pk;
    }
  }
}

// Head (sig / c_1): NT=1 blob, K=256 over hin; wave w rows [w*16,+16), w<4.
__device__ __forceinline__ f32x4 head_mt(const _Float16* __restrict__ hin,
                                         const _Float16* __restrict__ blob,
                                         int w, int lane) {
  const int l15  = lane & 15;
  const int quad = lane >> 4;
  const int s7   = l15 & 7;
  const int c1   = s7 >> 2;
  const int q3   = (quad ^ (s7 & 3));
  const _Float16* hb = hin + (w * 16 + l15) * 256 + q3 * 8;
  f32x4 res = (f32x4)0.f;
#pragma unroll
  for (int kc = 0; kc < 8; ++kc) {
    half8 a = *(const half8*)(blob + (kc * 64 + lane) * 8);
    half8 b = *(const half8*)(hb + ((kc ^ c1) << 5));
    res = MFMA_F16(a, b, res, 0, 0, 0);
  }
  return res;
}

__device__ __forceinline__ void pe_classify(int f, int nfeat, int& mode, int& c,
                                            int& use_cos, float& freq) {
  mode = 2; c = 0; use_cos = 0; freq = 0.f;
  if (f < 3) { mode = 0; c = f; }
  else if (f < nfeat) {
    int g = f - 3, li = g / 6, rem = g - li * 6;
    use_cos = (rem >= 3); c = use_cos ? rem - 3 : rem;
    freq = (float)(1 << li); mode = 1;
  }
}

// Positional encoding (512 threads): thread owns feature pair (2fp, 2fp+1)
// for 4 rows (r = t*16 + rb, rb = tid>>5 in [0,16)) -> one aligned b32 store
// per row; swizzle key loop-invariant (r&7 == rb&7).
__device__ __forceinline__ void pe_pass(_Float16* lds, const float* __restrict__ src,
                                        int row0, int tid, int nfeat) {
  const int fp = tid & 31;           // feature pair 0..31
  const int rb = tid >> 5;           // row base 0..15
  int m0, c0, u0; float q0;
  int m1, c1_, u1; float q1;
  pe_classify(fp * 2,     nfeat, m0, c0,  u0, q0);
  pe_classify(fp * 2 + 1, nfeat, m1, c1_, u1, q1);
  const int swz = (((fp >> 2) ^ (rb & 7)) << 3) | ((fp & 3) * 2);
#pragma unroll
  for (int t = 0; t < 4; ++t) {
    int r = t * 16 + rb;
    float v0 = 0.f, v1 = 0.f;
    if (m0 == 0) v0 = src[(row0 + r) * 3 + c0];
    else if (m0 == 1) {
      float a = src[(row0 + r) * 3 + c0] * q0;
      v0 = u0 ? __cosf(a) : __sinf(a);
    }
    if (m1 == 0) v1 = src[(row0 + r) * 3 + c1_];
    else if (m1 == 1) {
      float a = src[(row0 + r) * 3 + c1_] * q1;
      v1 = u1 ? __cosf(a) : __sinf(a);
    }
    half2v hv = { (_Float16)v0, (_Float16)v1 };
    *(half2v*)(lds + PE_OFF + r * 64 + swz) = hv;
  }
}

__global__ __launch_bounds__(512, 4) void nerf_kernel(
    const _Float16* __restrict__ ws, const float* __restrict__ x,
    const float* __restrict__ dirp, Ptr11 bp, float* __restrict__ out) {
  extern __shared__ _Float16 lds[];
  const int tid  = threadIdx.x;
  const int lane = tid & 63;
  const int w    = tid >> 6;       // wave 0..7 (= col-group cg)
  const int l15  = lane & 15;
  const int quad = lane >> 4;
  const int row0 = blockIdx.x * M_ROWS;

  _Float16* H0 = lds + H0_OFF;
  _Float16* H1 = lds + H1_OFF;

  // ---- pe_x -> PE buffer; biases -> LDS (f16, b32 stores, once) ----
  pe_pass(lds, x, row0, tid, 63);
  for (int i = tid; i < 1152; i += 512) {       // 9*256 halves as 1152 dwords
    int L = i >> 7, e2 = (i & 127) * 2;
    half2v hv = { (_Float16)bp.p[L][e2], (_Float16)bp.p[L][e2 + 1] };
    *(half2v*)(lds + BIAS_OFF + L * 256 + e2) = hv;
  }
  lds_barrier();

  // ---- G1: 63->256, 256->256 x4 (ReLU on all but last); H ping-pong ----
  do_layer<2, 0, true >(lds, H0, H0, ws + OFF_A[0], 0, w, lane); lds_barrier();
  do_layer<0, 8, true >(lds, H0, H1, ws + OFF_A[1], 1, w, lane); lds_barrier();
  do_layer<0, 8, true >(lds, H1, H0, ws + OFF_A[2], 2, w, lane); lds_barrier();
  do_layer<0, 8, true >(lds, H0, H1, ws + OFF_A[3], 3, w, lane); lds_barrier();
  do_layer<0, 8, false>(lds, H1, H0, ws + OFF_A[4], 4, w, lane); lds_barrier();  // f1 -> H0
  // ---- G2: [pe_x|f1] -> 256, 256->256, 256->256 (no ReLU on last) ----
  do_layer<2, 8, true >(lds, H0, H1, ws + OFF_A[5], 5, w, lane); lds_barrier();  // pe_x last use
  do_layer<0, 8, true >(lds, H1, H0, ws + OFF_A[6], 6, w, lane); lds_barrier();
  do_layer<0, 8, false>(lds, H0, H1, ws + OFF_A[7], 7, w, lane); lds_barrier();  // f2 -> H1

  // ---- sigma head reads f2 (waves 0..3); pe_d overwrites PE (pe_x dead) ----
  float sigv = 0.f;
  if (w < 4) {
    f32x4 sa = head_mt(H1, ws + OFF_A[10], w, lane);
    sigv = sa[0] + bp.p[10][0];   // valid in quad==0 lanes
  }
  pe_pass(lds, dirp, row0, tid, 39);
  lds_barrier();     // pe_d visible before c_0; sig H1-reads done (own-wave order)

  // ---- color: c_0 [pe_d|f2] -> H0 (ReLU), c_1 reads H0 (waves 0..3) ----
  do_layer<2, 8, true>(lds, H1, H0, ws + OFF_A[8], 8, w, lane); lds_barrier();
  if (w < 4) {
    f32x4 ca = head_mt(H0, ws + OFF_A[9], w, lane);
    if (quad == 0) {
      f32x4 o = { ca[0] + bp.p[9][0], ca[1] + bp.p[9][1], ca[2] + bp.p[9][2], sigv };
      *(f32x4*)(out + (size_t)(row0 + w * 16 + l15) * 4) = o;
    }
  }
}

}  // namespace

extern "C" void kernel_launch(void* const* d_in, const int* in_sizes, int n_in,
                              void* d_out, int out_size, void* d_ws, size_t ws_size,
                              hipStream_t stream) {
  const float* x   = (const float*)d_in[0];
  const float* dir = (const float*)d_in[1];
  Ptr11 wp, bp;
  for (int i = 0; i < 11; ++i) {
    wp.p[i] = (const float*)d_in[2 + 2 * i];
    bp.p[i] = (const float*)d_in[3 + 2 * i];
  }
  _Float16* ws = (_Float16*)d_ws;
  float* out = (float*)d_out;

  (void)hipFuncSetAttribute((const void*)nerf_kernel,
                            hipFuncAttributeMaxDynamicSharedMemorySize,
                            (int)LDS_BYTES);

  prep_kernel<<<(TOTAL_W + 255) / 256, 256, 0, stream>>>(wp, ws);
  nerf_kernel<<<262144 / M_ROWS, 512, LDS_BYTES, stream>>>(ws, x, dir, bp, out);
}